// Round 4
// baseline (477.951 us; speedup 1.0000x reference)
//
#include <hip/hip_runtime.h>
#include <math.h>

#define C1C 1e-4f       // 0.01^2
#define C2C 9e-4f       // 0.03^2
// Inputs: (32, 3, 512, 512) fp32; 8x8 patches of 64x64. plane = q*3 + c.
// Plane processed in two 32-col halves; LDS = 3*74*36*4 = 31968 B.
// OCCUPANCY MODEL (fit to r0-r3): resident blocks/CU = floor(256/VGPR)
// (effective per-SIMD VGPR pool ~256 for residency). LDS allows 5 blocks;
// VGPR is the binding limit. Target: natural VGPR <= 64 -> 4 blocks/CU.
// REGISTER CAP HISTORY (do not tighten): allocator targets 2x the 2nd
// launch_bounds arg and SPILLS to reach it: (256,5)->48 VGPR+830MB scratch,
// (256,4)->64+220MB scratch. Keep (256,3) (cap ~85, loose) and shrink the
// REAL live set instead: all conv windows sub-grouped to 14-wide (4 outputs
// per group) so H-pass peak = xs14+ys14+p14+hx8+hy8 ~ 58 floats.

// Gaussian weights g[k] = exp(-(k-5)^2/4.5)/sum, precomputed in fp64.
#define GW0 0.00102838f
#define GW1 0.00759876f
#define GW2 0.03600077f
#define GW3 0.10936069f
#define GW4 0.21300554f
#define GW5 0.26601173f
__device__ __forceinline__ float conv11(const float* w) {
    // w points at first tap of an 11-wide window
    float a = GW0 * (w[0] + w[10]);
    a = fmaf(GW1, w[1] + w[9], a);
    a = fmaf(GW2, w[2] + w[8], a);
    a = fmaf(GW3, w[3] + w[7], a);
    a = fmaf(GW4, w[4] + w[6], a);
    a = fmaf(GW5, w[5], a);
    return a;
}

#define SROWS 74   // 5 halo + 64 data + 5 halo
#define SSTR  36   // 32 cols + 4 pad (16B-aligned rows; +36 per row shifts
                   // bank by 4; 8-row stripe offset 8*36=288 ≡ 0 mod 32 ->
                   // half-waves alias 2-way = free)

// ---------------------------------------------------------------------------
// Fused: per (patch q, channel c) plane: separable 11x11 gaussian convs over
// two 32-col halves, SSIM-map sum, MSE partials.
// grid (2048, 3), block 256. LDS = 31968 B.
// ---------------------------------------------------------------------------
__global__ __launch_bounds__(256, 3) void ssim_fused_kernel(
    const float* __restrict__ A,  const float* __restrict__ Nimg,
    const float* __restrict__ GT, const float* __restrict__ G,
    const float* __restrict__ BG,
    float* __restrict__ ssim_sum, float* __restrict__ sa_sum,
    float* __restrict__ sbg_sum)
{
    __shared__ float S0[SROWS][SSTR];
    __shared__ float S1[SROWS][SSTR];
    __shared__ float S2[SROWS][SSTR];

    const int q  = blockIdx.x;          // patch 0..2047
    const int c  = blockIdx.y;          // channel 0..2
    const int b  = q >> 6;
    const int pp = q & 63;
    const int ph = pp >> 3;
    const int pw = pp & 7;
    // 32-bit element offsets: whole tensor is 25.2M floats < 2^32.
    const unsigned base = ((unsigned)(b * 3 + c) << 18)
                        + ((unsigned)(ph * 64) << 9)
                        + (unsigned)(pw * 64);
    const int t = threadIdx.x;

    // Zero the 5-row top/bottom halos of all three buffers (once; V-pass
    // never writes LDS and H-pass writes only rows 5..68, so halos persist).
    for (int i = t; i < 10 * SSTR; i += 256) {
        const int r  = i / SSTR;
        const int cc = i - r * SSTR;
        const int rr = (r < 5) ? r : 64 + r;        // rows 0..4, 69..73
        S0[rr][cc] = 0.f; S1[rr][cc] = 0.f; S2[rr][cc] = 0.f;
    }

    // Horizontal mapping: thread -> (row hr 0..63, 8-col segment hseg 0..3)
    const int hr   = t >> 2;
    const int hseg = t & 3;
    const int c0   = hseg << 3;               // local col in half: 0,8,16,24
    const unsigned rowBase = base + ((unsigned)hr << 9);
    // Vertical mapping: thread -> (col vcol 0..31, 8-row stripe)
    const int vcol = t & 31;
    const int vr0  = (t >> 5) << 3;           // padded window start row

    float accS = 0.f;

    for (int h = 0; h < 2; ++h) {
        const int g0 = (h << 5) + c0;         // global col of first output
        // ---------------- Horizontal pass (one half) -----------------------
        // Two sub-groups of 4 output cols each; 14-wide tap windows keep the
        // live set small (xs14+ys14+p14 transient, hx8+hy8 carried).
        float hx[8], hy[8];
        #pragma unroll
        for (int mm = 0; mm < 2; ++mm) {
            const int gb = g0 + 4 * mm;       // first output col of subgroup
            float xs[14], ys[14];
            // Aligned float4 loads cover cols gb-8 .. gb+11; taps used are
            // gb-5 .. gb+8 (xs[j] = image col gb-5+j).
            #pragma unroll
            for (int k = 0; k < 5; ++k) {
                const int cb = gb - 8 + 4 * k;
                float4 xv = make_float4(0.f, 0.f, 0.f, 0.f);
                float4 yv = make_float4(0.f, 0.f, 0.f, 0.f);
                if (cb >= 0 && cb < 64) {     // zero pad outside patch
                    xv = *(const float4*)(Nimg + rowBase + cb);
                    yv = *(const float4*)(GT   + rowBase + cb);
                }
                #pragma unroll
                for (int u = 0; u < 4; ++u) {
                    const int j = 4 * k + u - 3;   // xs index
                    if (j >= 0 && j < 14) {
                        xs[j] = (&xv.x)[u];
                        ys[j] = (&yv.x)[u];
                    }
                }
            }
            {
                float p[14];
                float4 o;
                #pragma unroll
                for (int i = 0; i < 14; ++i) p[i] = xs[i] * ys[i];   // x*y
                #pragma unroll
                for (int u = 0; u < 4; ++u) (&o.x)[u] = conv11(&p[u]);
                *(float4*)&S2[5 + hr][c0 + 4*mm] = o;
                #pragma unroll
                for (int i = 0; i < 14; ++i) p[i] = xs[i] * xs[i];   // x^2
                #pragma unroll
                for (int u = 0; u < 4; ++u) (&o.x)[u] = conv11(&p[u]);
                *(float4*)&S0[5 + hr][c0 + 4*mm] = o;
                #pragma unroll
                for (int i = 0; i < 14; ++i) p[i] = ys[i] * ys[i];   // y^2
                #pragma unroll
                for (int u = 0; u < 4; ++u) (&o.x)[u] = conv11(&p[u]);
                *(float4*)&S1[5 + hr][c0 + 4*mm] = o;
            }
            #pragma unroll
            for (int u = 0; u < 4; ++u) hx[4*mm + u] = conv11(&xs[u]);
            #pragma unroll
            for (int u = 0; u < 4; ++u) hy[4*mm + u] = conv11(&ys[u]);
        }
        __syncthreads();

        // ---------------- Vertical round 1: Exx, Eyy, Exy ------------------
        // Sub-grouped: 4 output rows per group, 14-row windows.
        float Exx[8], Eyy[8], Exy[8];
        #pragma unroll
        for (int vv = 0; vv < 2; ++vv) {
            const int r0 = vr0 + 4 * vv;
            float w[14];
            #pragma unroll
            for (int d = 0; d < 14; ++d) w[d] = S0[r0 + d][vcol];
            #pragma unroll
            for (int u = 0; u < 4; ++u) Exx[4*vv + u] = conv11(&w[u]);
            #pragma unroll
            for (int d = 0; d < 14; ++d) w[d] = S1[r0 + d][vcol];
            #pragma unroll
            for (int u = 0; u < 4; ++u) Eyy[4*vv + u] = conv11(&w[u]);
            #pragma unroll
            for (int d = 0; d < 14; ++d) w[d] = S2[r0 + d][vcol];
            #pragma unroll
            for (int u = 0; u < 4; ++u) Exy[4*vv + u] = conv11(&w[u]);
        }
        __syncthreads();

        // ---------------- Write hx, hy (kept in regs) ----------------------
        #pragma unroll
        for (int mm = 0; mm < 2; ++mm) {
            float4 o0, o1;
            #pragma unroll
            for (int u = 0; u < 4; ++u) {
                (&o0.x)[u] = hx[4*mm + u];
                (&o1.x)[u] = hy[4*mm + u];
            }
            *(float4*)&S0[5 + hr][c0 + 4*mm] = o0;
            *(float4*)&S1[5 + hr][c0 + 4*mm] = o1;
        }
        __syncthreads();

        // ---------------- Vertical round 2 + SSIM combine ------------------
        #pragma unroll
        for (int vv = 0; vv < 2; ++vv) {
            const int r0 = vr0 + 4 * vv;
            float w[14];
            float mu1[4];
            #pragma unroll
            for (int d = 0; d < 14; ++d) w[d] = S0[r0 + d][vcol];
            #pragma unroll
            for (int u = 0; u < 4; ++u) mu1[u] = conv11(&w[u]);
            #pragma unroll
            for (int d = 0; d < 14; ++d) w[d] = S1[r0 + d][vcol];
            #pragma unroll
            for (int u = 0; u < 4; ++u) {
                const float m2  = conv11(&w[u]);
                const float m1  = mu1[u];
                const float m1s = m1 * m1, m2s = m2 * m2, m12 = m1 * m2;
                const float s1  = Exx[4*vv + u] - m1s;
                const float s2v = Eyy[4*vv + u] - m2s;
                const float s12 = Exy[4*vv + u] - m12;
                const float num = (2.f * m12 + C1C) * (2.f * s12 + C2C);
                const float den = (m1s + m2s + C1C) * (s1 + s2v + C2C);
                accS += num / den;
            }
        }
        __syncthreads();      // buffers free for next half (or reduction)
    }

    // ---------------- Fused MSE partials over this plane -------------------
    float sa = 0.f, sbg = 0.f;
    #pragma unroll
    for (int it = 0; it < 4; ++it) {
        const int idx  = t + 256 * it;        // 0..1023 float4 slots
        const int row  = idx >> 4;
        const int col4 = (idx & 15) << 2;
        const unsigned off = base + ((unsigned)row << 9) + col4;
        const float4 av  = *(const float4*)(A  + off);
        const float4 gv  = *(const float4*)(G  + off);
        const float4 bgv = *(const float4*)(BG + off);
        float d0 = bgv.x - gv.x, d1 = bgv.y - gv.y, d2 = bgv.z - gv.z, d3 = bgv.w - gv.w;
        sbg += d0*d0 + d1*d1 + d2*d2 + d3*d3;
        float e0 = av.x - gv.x, e1 = av.y - gv.y, e2 = av.z - gv.z, e3 = av.w - gv.w;
        sa  += e0*e0 + e1*e1 + e2*e2 + e3*e3;
    }

    // ---------------- Block reduction of (accS, sa, sbg) -------------------
    #pragma unroll
    for (int off = 32; off; off >>= 1) {
        accS += __shfl_down(accS, off, 64);
        sa   += __shfl_down(sa,   off, 64);
        sbg  += __shfl_down(sbg,  off, 64);
    }
    const int wv = t >> 6;
    if ((t & 63) == 0) {
        S0[0][wv] = accS; S0[1][wv] = sa; S0[2][wv] = sbg;
    }
    __syncthreads();
    if (t == 0) {
        const int plane = q * 3 + c;
        ssim_sum[plane] = S0[0][0] + S0[0][1] + S0[0][2] + S0[0][3];
        sa_sum[plane]   = S0[1][0] + S0[1][1] + S0[1][2] + S0[1][3];
        sbg_sum[plane]  = S0[2][0] + S0[2][1] + S0[2][2] + S0[2][3];
    }
}

// ---------------------------------------------------------------------------
// Final combine: 1 block, 256 threads, no atomics, deterministic.
// ---------------------------------------------------------------------------
__global__ __launch_bounds__(256) void combine_kernel(
    const float* __restrict__ ssim_sum, const float* __restrict__ sa_sum,
    const float* __restrict__ sbg_sum, float* __restrict__ out)
{
    __shared__ float red[4];
    const int t = threadIdx.x;
    const float invN = 1.f / 12288.f;     // 3*64*64
    float acc = 0.f;
    #pragma unroll
    for (int r = 0; r < 8; ++r) {
        const int qq = t + 256 * r;       // patch 0..2047
        const float ss = ssim_sum[3*qq] + ssim_sum[3*qq+1] + ssim_sum[3*qq+2];
        const float sa = sa_sum[3*qq]   + sa_sum[3*qq+1]   + sa_sum[3*qq+2];
        const float sb = sbg_sum[3*qq]  + sbg_sum[3*qq+1]  + sbg_sum[3*qq+2];
        const float ssim = ss * invN;
        const float diff = fminf(1.f - ssim, 1.f);     // LD = 1.0
        acc += diff * (sb * invN) + (1.f - diff) * (sa * invN);
    }
    #pragma unroll
    for (int off = 32; off; off >>= 1) acc += __shfl_down(acc, off, 64);
    if ((t & 63) == 0) red[t >> 6] = acc;
    __syncthreads();
    if (t == 0) out[0] = red[0] + red[1] + red[2] + red[3];
}

extern "C" void kernel_launch(void* const* d_in, const int* in_sizes, int n_in,
                              void* d_out, int out_size, void* d_ws, size_t ws_size,
                              hipStream_t stream) {
    const float* A  = (const float*)d_in[0];
    const float* Nn = (const float*)d_in[1];
    const float* GT = (const float*)d_in[2];
    const float* G  = (const float*)d_in[3];
    const float* BG = (const float*)d_in[4];
    float* out      = (float*)d_out;

    float* ssim_sum = (float*)d_ws;            // 6144 floats
    float* sa_sum   = ssim_sum + 6144;         // 6144 floats
    float* sbg_sum  = ssim_sum + 12288;        // 6144 floats

    ssim_fused_kernel<<<dim3(2048, 3), 256, 0, stream>>>(
        A, Nn, GT, G, BG, ssim_sum, sa_sum, sbg_sum);
    combine_kernel<<<1, 256, 0, stream>>>(ssim_sum, sa_sum, sbg_sum, out);
}

// Round 5
// 444.577 us; speedup vs baseline: 1.0751x; 1.0751x over previous
//
#include <hip/hip_runtime.h>
#include <math.h>

#define C1C 1e-4f       // 0.01^2
#define C2C 9e-4f       // 0.03^2
// Inputs: (32, 3, 512, 512) fp32; 8x8 patches of 64x64. plane = q*3 + c.
// Plane processed in two 32-col halves. FIVE LDS buffers (x, y, xy, xx, yy
// H-conv results) so the vertical pass runs in ONE phase: 2 barriers per
// half instead of 4. LDS = 5*74*36*4 = 53280 B -> 3 blocks/CU, which equals
// the VGPR-limited residency anyway (measured r0-r4), so the extra LDS is
// free and the barrier count halves.
// REGISTER CAP HISTORY (do not tighten): allocator targets 2x the 2nd
// launch_bounds arg and SPILLS to reach it: (256,5)->48 VGPR+830MB scratch,
// (256,4)->64+220MB scratch. Keep (256,3) loose; natural alloc ~70-80, no
// spill. Live-set shaving below that failed (r4): scheduler re-merges.
// dur*VALUBusy ~= 93us constant across r0/r3/r4 -> duration is stall-set;
// this round attacks barrier drains.

// Gaussian weights g[k] = exp(-(k-5)^2/4.5)/sum, precomputed in fp64.
#define GW0 0.00102838f
#define GW1 0.00759876f
#define GW2 0.03600077f
#define GW3 0.10936069f
#define GW4 0.21300554f
#define GW5 0.26601173f
__device__ __forceinline__ float conv11(const float* w) {
    // w points at first tap of an 11-wide window
    float a = GW0 * (w[0] + w[10]);
    a = fmaf(GW1, w[1] + w[9], a);
    a = fmaf(GW2, w[2] + w[8], a);
    a = fmaf(GW3, w[3] + w[7], a);
    a = fmaf(GW4, w[4] + w[6], a);
    a = fmaf(GW5, w[5], a);
    return a;
}

#define SROWS 74   // 5 halo + 64 data + 5 halo
#define SSTR  36   // 32 cols + 4 pad (16B-aligned rows; +36 per row shifts
                   // bank by 4; 8-row stripe offset 8*36=288 ≡ 0 mod 32 ->
                   // half-waves alias 2-way = free; measured conflicts 0)

// ---------------------------------------------------------------------------
// Fused: per (patch q, channel c) plane: separable 11x11 gaussian convs over
// two 32-col halves, SSIM-map sum, MSE partials.
// grid (2048, 3), block 256. LDS = 53280 B.
// ---------------------------------------------------------------------------
__global__ __launch_bounds__(256, 3) void ssim_fused_kernel(
    const float* __restrict__ A,  const float* __restrict__ Nimg,
    const float* __restrict__ GT, const float* __restrict__ G,
    const float* __restrict__ BG,
    float* __restrict__ ssim_sum, float* __restrict__ sa_sum,
    float* __restrict__ sbg_sum)
{
    __shared__ float S0[SROWS][SSTR];   // conv(x*x)
    __shared__ float S1[SROWS][SSTR];   // conv(y*y)
    __shared__ float S2[SROWS][SSTR];   // conv(x*y)
    __shared__ float S3[SROWS][SSTR];   // conv(x)
    __shared__ float S4[SROWS][SSTR];   // conv(y)

    const int q  = blockIdx.x;          // patch 0..2047
    const int c  = blockIdx.y;          // channel 0..2
    const int b  = q >> 6;
    const int pp = q & 63;
    const int ph = pp >> 3;
    const int pw = pp & 7;
    // 32-bit element offsets: whole tensor is 25.2M floats < 2^32.
    const unsigned base = ((unsigned)(b * 3 + c) << 18)
                        + ((unsigned)(ph * 64) << 9)
                        + (unsigned)(pw * 64);
    const int t = threadIdx.x;

    // Zero the 5-row top/bottom halos of all five buffers (once; V-pass
    // never writes LDS and H-pass writes only rows 5..68, so halos persist).
    for (int i = t; i < 10 * SSTR; i += 256) {
        const int r  = i / SSTR;
        const int cc = i - r * SSTR;
        const int rr = (r < 5) ? r : 64 + r;        // rows 0..4, 69..73
        S0[rr][cc] = 0.f; S1[rr][cc] = 0.f; S2[rr][cc] = 0.f;
        S3[rr][cc] = 0.f; S4[rr][cc] = 0.f;
    }

    // Horizontal mapping: thread -> (row hr 0..63, 8-col segment hseg 0..3)
    const int hr   = t >> 2;
    const int hseg = t & 3;
    const int c0   = hseg << 3;               // local col in half: 0,8,16,24
    const unsigned rowBase = base + ((unsigned)hr << 9);
    // Vertical mapping: thread -> (col vcol 0..31, 8-row stripe)
    const int vcol = t & 31;
    const int vr0  = (t >> 5) << 3;           // padded window start row

    float accS = 0.f;

    for (int h = 0; h < 2; ++h) {
        const int g0 = (h << 5) + c0;         // global col of first output
        // ---------------- Horizontal pass (one half) -----------------------
        // Window taps for global cols g0-5 .. g0+12 (18 floats); aligned
        // float4 loads cover g0-8 .. g0+15, extras discarded at compile time.
        float xs[18], ys[18];
        #pragma unroll
        for (int m = 0; m < 6; ++m) {
            const int cb = g0 - 8 + 4 * m;    // global col of this float4
            float4 xv = make_float4(0.f, 0.f, 0.f, 0.f);
            float4 yv = make_float4(0.f, 0.f, 0.f, 0.f);
            if (cb >= 0 && cb < 64) {         // zero pad outside patch
                xv = *(const float4*)(Nimg + rowBase + cb);
                yv = *(const float4*)(GT   + rowBase + cb);
            }
            #pragma unroll
            for (int u = 0; u < 4; ++u) {
                const int j = 4 * m + u - 3;  // xs index (col g0-5+j)
                if (j >= 0 && j < 18) {
                    xs[j] = (&xv.x)[u];
                    ys[j] = (&yv.x)[u];
                }
            }
        }

        {
            // p[i] = product at xs index i; output u reads p[u..u+10].
            float p[18];
            #pragma unroll
            for (int i = 0; i < 18; ++i) p[i] = xs[i] * ys[i];   // x*y
            #pragma unroll
            for (int mm = 0; mm < 2; ++mm) {
                float4 o;
                #pragma unroll
                for (int u = 0; u < 4; ++u) (&o.x)[u] = conv11(&p[4*mm + u]);
                *(float4*)&S2[5 + hr][c0 + 4*mm] = o;
            }
            #pragma unroll
            for (int i = 0; i < 18; ++i) p[i] = xs[i] * xs[i];   // x^2
            #pragma unroll
            for (int mm = 0; mm < 2; ++mm) {
                float4 o;
                #pragma unroll
                for (int u = 0; u < 4; ++u) (&o.x)[u] = conv11(&p[4*mm + u]);
                *(float4*)&S0[5 + hr][c0 + 4*mm] = o;
            }
            #pragma unroll
            for (int i = 0; i < 18; ++i) p[i] = ys[i] * ys[i];   // y^2
            #pragma unroll
            for (int mm = 0; mm < 2; ++mm) {
                float4 o;
                #pragma unroll
                for (int u = 0; u < 4; ++u) (&o.x)[u] = conv11(&p[4*mm + u]);
                *(float4*)&S1[5 + hr][c0 + 4*mm] = o;
            }
            // conv(x), conv(y) straight to LDS (no register carry)
            #pragma unroll
            for (int mm = 0; mm < 2; ++mm) {
                float4 o0, o1;
                #pragma unroll
                for (int u = 0; u < 4; ++u) {
                    (&o0.x)[u] = conv11(&xs[4*mm + u]);
                    (&o1.x)[u] = conv11(&ys[4*mm + u]);
                }
                *(float4*)&S3[5 + hr][c0 + 4*mm] = o0;
                *(float4*)&S4[5 + hr][c0 + 4*mm] = o1;
            }
        }
        __syncthreads();

        // ---------------- Vertical pass: all 5 convs + SSIM ----------------
        {
            float Exx[8], Eyy[8], Exy[8], mu1[8];
            float w[18];
            #pragma unroll
            for (int d = 0; d < 18; ++d) w[d] = S0[vr0 + d][vcol];
            #pragma unroll
            for (int o = 0; o < 8; ++o) Exx[o] = conv11(&w[o]);
            #pragma unroll
            for (int d = 0; d < 18; ++d) w[d] = S1[vr0 + d][vcol];
            #pragma unroll
            for (int o = 0; o < 8; ++o) Eyy[o] = conv11(&w[o]);
            #pragma unroll
            for (int d = 0; d < 18; ++d) w[d] = S2[vr0 + d][vcol];
            #pragma unroll
            for (int o = 0; o < 8; ++o) Exy[o] = conv11(&w[o]);
            #pragma unroll
            for (int d = 0; d < 18; ++d) w[d] = S3[vr0 + d][vcol];
            #pragma unroll
            for (int o = 0; o < 8; ++o) mu1[o] = conv11(&w[o]);
            #pragma unroll
            for (int d = 0; d < 18; ++d) w[d] = S4[vr0 + d][vcol];
            #pragma unroll
            for (int o = 0; o < 8; ++o) {
                const float m2  = conv11(&w[o]);
                const float m1  = mu1[o];
                const float m1s = m1 * m1, m2s = m2 * m2, m12 = m1 * m2;
                const float s1  = Exx[o] - m1s;
                const float s2v = Eyy[o] - m2s;
                const float s12 = Exy[o] - m12;
                const float num = (2.f * m12 + C1C) * (2.f * s12 + C2C);
                const float den = (m1s + m2s + C1C) * (s1 + s2v + C2C);
                accS += num / den;
            }
        }
        __syncthreads();      // buffers free for next half (or reduction)
    }

    // ---------------- Fused MSE partials over this plane -------------------
    float sa = 0.f, sbg = 0.f;
    #pragma unroll
    for (int it = 0; it < 4; ++it) {
        const int idx  = t + 256 * it;        // 0..1023 float4 slots
        const int row  = idx >> 4;
        const int col4 = (idx & 15) << 2;
        const unsigned off = base + ((unsigned)row << 9) + col4;
        const float4 av  = *(const float4*)(A  + off);
        const float4 gv  = *(const float4*)(G  + off);
        const float4 bgv = *(const float4*)(BG + off);
        float d0 = bgv.x - gv.x, d1 = bgv.y - gv.y, d2 = bgv.z - gv.z, d3 = bgv.w - gv.w;
        sbg += d0*d0 + d1*d1 + d2*d2 + d3*d3;
        float e0 = av.x - gv.x, e1 = av.y - gv.y, e2 = av.z - gv.z, e3 = av.w - gv.w;
        sa  += e0*e0 + e1*e1 + e2*e2 + e3*e3;
    }

    // ---------------- Block reduction of (accS, sa, sbg) -------------------
    #pragma unroll
    for (int off = 32; off; off >>= 1) {
        accS += __shfl_down(accS, off, 64);
        sa   += __shfl_down(sa,   off, 64);
        sbg  += __shfl_down(sbg,  off, 64);
    }
    const int wv = t >> 6;
    if ((t & 63) == 0) {
        S0[0][wv] = accS; S0[1][wv] = sa; S0[2][wv] = sbg;
    }
    __syncthreads();
    if (t == 0) {
        const int plane = q * 3 + c;
        ssim_sum[plane] = S0[0][0] + S0[0][1] + S0[0][2] + S0[0][3];
        sa_sum[plane]   = S0[1][0] + S0[1][1] + S0[1][2] + S0[1][3];
        sbg_sum[plane]  = S0[2][0] + S0[2][1] + S0[2][2] + S0[2][3];
    }
}

// ---------------------------------------------------------------------------
// Final combine: 1 block, 256 threads, no atomics, deterministic.
// ---------------------------------------------------------------------------
__global__ __launch_bounds__(256) void combine_kernel(
    const float* __restrict__ ssim_sum, const float* __restrict__ sa_sum,
    const float* __restrict__ sbg_sum, float* __restrict__ out)
{
    __shared__ float red[4];
    const int t = threadIdx.x;
    const float invN = 1.f / 12288.f;     // 3*64*64
    float acc = 0.f;
    #pragma unroll
    for (int r = 0; r < 8; ++r) {
        const int qq = t + 256 * r;       // patch 0..2047
        const float ss = ssim_sum[3*qq] + ssim_sum[3*qq+1] + ssim_sum[3*qq+2];
        const float sa = sa_sum[3*qq]   + sa_sum[3*qq+1]   + sa_sum[3*qq+2];
        const float sb = sbg_sum[3*qq]  + sbg_sum[3*qq+1]  + sbg_sum[3*qq+2];
        const float ssim = ss * invN;
        const float diff = fminf(1.f - ssim, 1.f);     // LD = 1.0
        acc += diff * (sb * invN) + (1.f - diff) * (sa * invN);
    }
    #pragma unroll
    for (int off = 32; off; off >>= 1) acc += __shfl_down(acc, off, 64);
    if ((t & 63) == 0) red[t >> 6] = acc;
    __syncthreads();
    if (t == 0) out[0] = red[0] + red[1] + red[2] + red[3];
}

extern "C" void kernel_launch(void* const* d_in, const int* in_sizes, int n_in,
                              void* d_out, int out_size, void* d_ws, size_t ws_size,
                              hipStream_t stream) {
    const float* A  = (const float*)d_in[0];
    const float* Nn = (const float*)d_in[1];
    const float* GT = (const float*)d_in[2];
    const float* G  = (const float*)d_in[3];
    const float* BG = (const float*)d_in[4];
    float* out      = (float*)d_out;

    float* ssim_sum = (float*)d_ws;            // 6144 floats
    float* sa_sum   = ssim_sum + 6144;         // 6144 floats
    float* sbg_sum  = ssim_sum + 12288;        // 6144 floats

    ssim_fused_kernel<<<dim3(2048, 3), 256, 0, stream>>>(
        A, Nn, GT, G, BG, ssim_sum, sa_sum, sbg_sum);
    combine_kernel<<<1, 256, 0, stream>>>(ssim_sum, sa_sum, sbg_sum, out);
}

// Round 6
// 439.994 us; speedup vs baseline: 1.0863x; 1.0104x over previous
//
#include <hip/hip_runtime.h>
#include <math.h>

#define C1C 1e-4f       // 0.01^2
#define C2C 9e-4f       // 0.03^2
// Inputs: (32, 3, 512, 512) fp32; 8x8 patches of 64x64. plane = q*3 + c.
// FOUR-CONV SSIM: in basis s=x+y, d=x-y,
//   a = conv(s) = mu1+mu2, b = conv(d) = mu1-mu2,
//   u = conv(s^2), v = conv(d^2):
//   2*mu1mu2   = (a^2-b^2)/2     mu1^2+mu2^2 = (a^2+b^2)/2
//   2*sigma12+C2 = (u-v)/2 - (a^2-b^2)/2 + C2
//   sig1+sig2+C2 = (u+v)/2 - (a^2+b^2)/2 + C2
// -> 4 separable convs instead of 5: -20% conv FLOPs, -20% LDS ops/buffers.
// Plane processed in two 32-col halves; LDS = 4*74*36*4 = 42624 B.
// 5-row zeroed halos top+bottom keep the vertical conv branch-free.
// MEASURED INVARIANTS (r0-r5): dur*VALUBusy ~= 93us (work-bound at fixed
// ~49% busy); occupancy fits waves/SIMD = floor(256/VGPR) -> need VGPR<=85
// for 3 waves/SIMD. DO NOT tighten launch_bounds: (256,5)/(256,4) caused
// spill cascades (48/64 VGPR + hundreds of MB scratch). Keep (256,3).

// Gaussian weights g[k] = exp(-(k-5)^2/4.5)/sum, precomputed in fp64.
#define GW0 0.00102838f
#define GW1 0.00759876f
#define GW2 0.03600077f
#define GW3 0.10936069f
#define GW4 0.21300554f
#define GW5 0.26601173f
__device__ __forceinline__ float conv11(const float* w) {
    // w points at first tap of an 11-wide window
    float a = GW0 * (w[0] + w[10]);
    a = fmaf(GW1, w[1] + w[9], a);
    a = fmaf(GW2, w[2] + w[8], a);
    a = fmaf(GW3, w[3] + w[7], a);
    a = fmaf(GW4, w[4] + w[6], a);
    a = fmaf(GW5, w[5], a);
    return a;
}

#define SROWS 74   // 5 halo + 64 data + 5 halo
#define SSTR  36   // 32 cols + 4 pad (16B-aligned rows; +36 per row shifts
                   // bank by 4; 8-row stripe offset 8*36=288 ≡ 0 mod 32 ->
                   // half-waves alias 2-way = free; measured conflicts 0)

// ---------------------------------------------------------------------------
// Fused: per (patch q, channel c) plane: 4 separable 11x11 gaussian convs
// over two 32-col halves, SSIM-map sum, MSE partials.
// grid (2048, 3), block 256. LDS = 42624 B.
// ---------------------------------------------------------------------------
__global__ __launch_bounds__(256, 3) void ssim_fused_kernel(
    const float* __restrict__ A,  const float* __restrict__ Nimg,
    const float* __restrict__ GT, const float* __restrict__ G,
    const float* __restrict__ BG,
    float* __restrict__ ssim_sum, float* __restrict__ sa_sum,
    float* __restrict__ sbg_sum)
{
    __shared__ float S0[SROWS][SSTR];   // conv(s^2)
    __shared__ float S1[SROWS][SSTR];   // conv(d^2)
    __shared__ float S2[SROWS][SSTR];   // conv(s)
    __shared__ float S3[SROWS][SSTR];   // conv(d)

    const int q  = blockIdx.x;          // patch 0..2047
    const int c  = blockIdx.y;          // channel 0..2
    const int b  = q >> 6;
    const int pp = q & 63;
    const int ph = pp >> 3;
    const int pw = pp & 7;
    // 32-bit element offsets: whole tensor is 25.2M floats < 2^32.
    const unsigned base = ((unsigned)(b * 3 + c) << 18)
                        + ((unsigned)(ph * 64) << 9)
                        + (unsigned)(pw * 64);
    const int t = threadIdx.x;

    // Zero the 5-row top/bottom halos of all four buffers (once; V-pass
    // never writes LDS and H-pass writes only rows 5..68, so halos persist).
    for (int i = t; i < 10 * SSTR; i += 256) {
        const int r  = i / SSTR;
        const int cc = i - r * SSTR;
        const int rr = (r < 5) ? r : 64 + r;        // rows 0..4, 69..73
        S0[rr][cc] = 0.f; S1[rr][cc] = 0.f;
        S2[rr][cc] = 0.f; S3[rr][cc] = 0.f;
    }

    // Horizontal mapping: thread -> (row hr 0..63, 8-col segment hseg 0..3)
    const int hr   = t >> 2;
    const int hseg = t & 3;
    const int c0   = hseg << 3;               // local col in half: 0,8,16,24
    const unsigned rowBase = base + ((unsigned)hr << 9);
    // Vertical mapping: thread -> (col vcol 0..31, 8-row stripe)
    const int vcol = t & 31;
    const int vr0  = (t >> 5) << 3;           // padded window start row

    float accS = 0.f;

    for (int h = 0; h < 2; ++h) {
        const int g0 = (h << 5) + c0;         // global col of first output
        // ---------------- Horizontal pass (one half) -----------------------
        // Window taps for global cols g0-5 .. g0+12 (18 floats); aligned
        // float4 loads cover g0-8 .. g0+15, extras discarded at compile time.
        // Build s=x+y, d=x-y at extraction; x,y never stay live.
        float s[18], d[18];
        #pragma unroll
        for (int m = 0; m < 6; ++m) {
            const int cb = g0 - 8 + 4 * m;    // global col of this float4
            float4 xv = make_float4(0.f, 0.f, 0.f, 0.f);
            float4 yv = make_float4(0.f, 0.f, 0.f, 0.f);
            if (cb >= 0 && cb < 64) {         // zero pad outside patch
                xv = *(const float4*)(Nimg + rowBase + cb);
                yv = *(const float4*)(GT   + rowBase + cb);
            }
            #pragma unroll
            for (int u = 0; u < 4; ++u) {
                const int j = 4 * m + u - 3;  // window index (col g0-5+j)
                if (j >= 0 && j < 18) {
                    s[j] = (&xv.x)[u] + (&yv.x)[u];
                    d[j] = (&xv.x)[u] - (&yv.x)[u];
                }
            }
        }

        {
            // p[i] = squared term at window index i; output u reads p[u..u+10].
            float p[18];
            #pragma unroll
            for (int i = 0; i < 18; ++i) p[i] = s[i] * s[i];   // s^2
            #pragma unroll
            for (int mm = 0; mm < 2; ++mm) {
                float4 o;
                #pragma unroll
                for (int u = 0; u < 4; ++u) (&o.x)[u] = conv11(&p[4*mm + u]);
                *(float4*)&S0[5 + hr][c0 + 4*mm] = o;
            }
            #pragma unroll
            for (int i = 0; i < 18; ++i) p[i] = d[i] * d[i];   // d^2
            #pragma unroll
            for (int mm = 0; mm < 2; ++mm) {
                float4 o;
                #pragma unroll
                for (int u = 0; u < 4; ++u) (&o.x)[u] = conv11(&p[4*mm + u]);
                *(float4*)&S1[5 + hr][c0 + 4*mm] = o;
            }
            // conv(s), conv(d) straight to LDS (no register carry)
            #pragma unroll
            for (int mm = 0; mm < 2; ++mm) {
                float4 o0, o1;
                #pragma unroll
                for (int u = 0; u < 4; ++u) {
                    (&o0.x)[u] = conv11(&s[4*mm + u]);
                    (&o1.x)[u] = conv11(&d[4*mm + u]);
                }
                *(float4*)&S2[5 + hr][c0 + 4*mm] = o0;
                *(float4*)&S3[5 + hr][c0 + 4*mm] = o1;
            }
        }
        __syncthreads();

        // ---------------- Vertical pass: 4 convs + SSIM --------------------
        {
            float av[8], bv[8], uv[8];
            float w[18];
            #pragma unroll
            for (int dd = 0; dd < 18; ++dd) w[dd] = S2[vr0 + dd][vcol];
            #pragma unroll
            for (int o = 0; o < 8; ++o) av[o] = conv11(&w[o]);
            #pragma unroll
            for (int dd = 0; dd < 18; ++dd) w[dd] = S3[vr0 + dd][vcol];
            #pragma unroll
            for (int o = 0; o < 8; ++o) bv[o] = conv11(&w[o]);
            #pragma unroll
            for (int dd = 0; dd < 18; ++dd) w[dd] = S0[vr0 + dd][vcol];
            #pragma unroll
            for (int o = 0; o < 8; ++o) uv[o] = conv11(&w[o]);
            #pragma unroll
            for (int dd = 0; dd < 18; ++dd) w[dd] = S1[vr0 + dd][vcol];
            #pragma unroll
            for (int o = 0; o < 8; ++o) {
                const float vvv = conv11(&w[o]);        // v = conv(d^2) vert
                const float A2  = av[o] * av[o];
                const float B2  = bv[o] * bv[o];
                const float twoM12 = 0.5f * (A2 - B2);  // 2*mu1*mu2
                const float sumSq  = 0.5f * (A2 + B2);  // mu1^2+mu2^2
                const float numL = twoM12 + C1C;
                const float denL = sumSq  + C1C;
                const float numR = fmaf(0.5f, uv[o] - vvv, C2C - twoM12);
                const float denR = fmaf(0.5f, uv[o] + vvv, C2C - sumSq);
                // rcp: rel err ~1e-6, final scalar well within tolerance
                accS += (numL * numR) * __builtin_amdgcn_rcpf(denL * denR);
            }
        }
        __syncthreads();      // buffers free for next half (or reduction)
    }

    // ---------------- Fused MSE partials over this plane -------------------
    float sa = 0.f, sbg = 0.f;
    #pragma unroll
    for (int it = 0; it < 4; ++it) {
        const int idx  = t + 256 * it;        // 0..1023 float4 slots
        const int row  = idx >> 4;
        const int col4 = (idx & 15) << 2;
        const unsigned off = base + ((unsigned)row << 9) + col4;
        const float4 av  = *(const float4*)(A  + off);
        const float4 gv  = *(const float4*)(G  + off);
        const float4 bgv = *(const float4*)(BG + off);
        float d0 = bgv.x - gv.x, d1 = bgv.y - gv.y, d2 = bgv.z - gv.z, d3 = bgv.w - gv.w;
        sbg += d0*d0 + d1*d1 + d2*d2 + d3*d3;
        float e0 = av.x - gv.x, e1 = av.y - gv.y, e2 = av.z - gv.z, e3 = av.w - gv.w;
        sa  += e0*e0 + e1*e1 + e2*e2 + e3*e3;
    }

    // ---------------- Block reduction of (accS, sa, sbg) -------------------
    #pragma unroll
    for (int off = 32; off; off >>= 1) {
        accS += __shfl_down(accS, off, 64);
        sa   += __shfl_down(sa,   off, 64);
        sbg  += __shfl_down(sbg,  off, 64);
    }
    const int wv = t >> 6;
    if ((t & 63) == 0) {
        S0[0][wv] = accS; S0[1][wv] = sa; S0[2][wv] = sbg;
    }
    __syncthreads();
    if (t == 0) {
        const int plane = q * 3 + c;
        ssim_sum[plane] = S0[0][0] + S0[0][1] + S0[0][2] + S0[0][3];
        sa_sum[plane]   = S0[1][0] + S0[1][1] + S0[1][2] + S0[1][3];
        sbg_sum[plane]  = S0[2][0] + S0[2][1] + S0[2][2] + S0[2][3];
    }
}

// ---------------------------------------------------------------------------
// Final combine: 1 block, 256 threads, no atomics, deterministic.
// ---------------------------------------------------------------------------
__global__ __launch_bounds__(256) void combine_kernel(
    const float* __restrict__ ssim_sum, const float* __restrict__ sa_sum,
    const float* __restrict__ sbg_sum, float* __restrict__ out)
{
    __shared__ float red[4];
    const int t = threadIdx.x;
    const float invN = 1.f / 12288.f;     // 3*64*64
    float acc = 0.f;
    #pragma unroll
    for (int r = 0; r < 8; ++r) {
        const int qq = t + 256 * r;       // patch 0..2047
        const float ss = ssim_sum[3*qq] + ssim_sum[3*qq+1] + ssim_sum[3*qq+2];
        const float sa = sa_sum[3*qq]   + sa_sum[3*qq+1]   + sa_sum[3*qq+2];
        const float sb = sbg_sum[3*qq]  + sbg_sum[3*qq+1]  + sbg_sum[3*qq+2];
        const float ssim = ss * invN;
        const float diff = fminf(1.f - ssim, 1.f);     // LD = 1.0
        acc += diff * (sb * invN) + (1.f - diff) * (sa * invN);
    }
    #pragma unroll
    for (int off = 32; off; off >>= 1) acc += __shfl_down(acc, off, 64);
    if ((t & 63) == 0) red[t >> 6] = acc;
    __syncthreads();
    if (t == 0) out[0] = red[0] + red[1] + red[2] + red[3];
}

extern "C" void kernel_launch(void* const* d_in, const int* in_sizes, int n_in,
                              void* d_out, int out_size, void* d_ws, size_t ws_size,
                              hipStream_t stream) {
    const float* A  = (const float*)d_in[0];
    const float* Nn = (const float*)d_in[1];
    const float* GT = (const float*)d_in[2];
    const float* G  = (const float*)d_in[3];
    const float* BG = (const float*)d_in[4];
    float* out      = (float*)d_out;

    float* ssim_sum = (float*)d_ws;            // 6144 floats
    float* sa_sum   = ssim_sum + 6144;         // 6144 floats
    float* sbg_sum  = ssim_sum + 12288;        // 6144 floats

    ssim_fused_kernel<<<dim3(2048, 3), 256, 0, stream>>>(
        A, Nn, GT, G, BG, ssim_sum, sa_sum, sbg_sum);
    combine_kernel<<<1, 256, 0, stream>>>(ssim_sum, sa_sum, sbg_sum, out);
}

// Round 7
// 434.650 us; speedup vs baseline: 1.0996x; 1.0123x over previous
//
#include <hip/hip_runtime.h>
#include <math.h>

#define C1C 1e-4f       // 0.01^2
#define C2C 9e-4f       // 0.03^2
// Inputs: (32, 3, 512, 512) fp32; 8x8 patches of 64x64. plane = q*3 + c.
// FOUR-CONV SSIM: in basis s=x+y, d=x-y,
//   a = conv(s) = mu1+mu2, b = conv(d) = mu1-mu2,
//   u = conv(s^2), v = conv(d^2):
//   2*mu1mu2     = (a^2-b^2)/2    mu1^2+mu2^2 = (a^2+b^2)/2
//   2*sigma12+C2 = (u-v)/2 - (a^2-b^2)/2 + C2
//   sig1+sig2+C2 = (u+v)/2 - (a^2+b^2)/2 + C2
// Plane processed in two 32-col halves; LDS = 4*74*36*4 = 42624 B.
// MEASURED MODEL (r0-r6): dur = VALU-work/busy; work=72us (r6); stall ~108us
// constant, set by occupancy. Occupancy: blocks/CU = floor(256/VGPR) ->
// VGPR<=64 gives 4 blocks (41% occ, r2); 65..85 gives 3 (29%). This round:
// register diet to land <=64 NATURALLY. DO NOT tighten launch_bounds:
// (256,5)/(256,4) forced caps -> spill cascade (hundreds of MB scratch).
// H-pass: s,d built at load (x,y never arrays); conv(s)->square in place->
// conv(s^2) ordering removes the p[18] temp entirely. Peak live ~36.
// V-pass: fold av,bv into t2,ss as bv streams; last buffer streams into
// the SSIM combine. Peak live ~42.

// Gaussian weights g[k] = exp(-(k-5)^2/4.5)/sum, precomputed in fp64.
#define GW0 0.00102838f
#define GW1 0.00759876f
#define GW2 0.03600077f
#define GW3 0.10936069f
#define GW4 0.21300554f
#define GW5 0.26601173f
__device__ __forceinline__ float conv11(const float* w) {
    // w points at first tap of an 11-wide window
    float a = GW0 * (w[0] + w[10]);
    a = fmaf(GW1, w[1] + w[9], a);
    a = fmaf(GW2, w[2] + w[8], a);
    a = fmaf(GW3, w[3] + w[7], a);
    a = fmaf(GW4, w[4] + w[6], a);
    a = fmaf(GW5, w[5], a);
    return a;
}

#define SROWS 74   // 5 halo + 64 data + 5 halo
#define SSTR  36   // 32 cols + 4 pad (16B-aligned rows; +36 per row shifts
                   // bank by 4; 8-row stripe offset 8*36=288 ≡ 0 mod 32 ->
                   // half-waves alias 2-way = free; measured conflicts 0)

// ---------------------------------------------------------------------------
// Fused: per (patch q, channel c) plane: 4 separable 11x11 gaussian convs
// over two 32-col halves, SSIM-map sum, MSE partials.
// grid (2048, 3), block 256. LDS = 42624 B.
// ---------------------------------------------------------------------------
__global__ __launch_bounds__(256, 3) void ssim_fused_kernel(
    const float* __restrict__ A,  const float* __restrict__ Nimg,
    const float* __restrict__ GT, const float* __restrict__ G,
    const float* __restrict__ BG,
    float* __restrict__ ssim_sum, float* __restrict__ sa_sum,
    float* __restrict__ sbg_sum)
{
    __shared__ float S0[SROWS][SSTR];   // conv(s^2)
    __shared__ float S1[SROWS][SSTR];   // conv(d^2)
    __shared__ float S2[SROWS][SSTR];   // conv(s)
    __shared__ float S3[SROWS][SSTR];   // conv(d)

    const int q  = blockIdx.x;          // patch 0..2047
    const int c  = blockIdx.y;          // channel 0..2
    const int b  = q >> 6;
    const int pp = q & 63;
    const int ph = pp >> 3;
    const int pw = pp & 7;
    // 32-bit element offsets: whole tensor is 25.2M floats < 2^32.
    const unsigned base = ((unsigned)(b * 3 + c) << 18)
                        + ((unsigned)(ph * 64) << 9)
                        + (unsigned)(pw * 64);
    const int t = threadIdx.x;

    // Zero the 5-row top/bottom halos of all four buffers (once; V-pass
    // never writes LDS and H-pass writes only rows 5..68, so halos persist).
    for (int i = t; i < 10 * SSTR; i += 256) {
        const int r  = i / SSTR;
        const int cc = i - r * SSTR;
        const int rr = (r < 5) ? r : 64 + r;        // rows 0..4, 69..73
        S0[rr][cc] = 0.f; S1[rr][cc] = 0.f;
        S2[rr][cc] = 0.f; S3[rr][cc] = 0.f;
    }

    // Horizontal mapping: thread -> (row hr 0..63, 8-col segment hseg 0..3)
    const int hr   = t >> 2;
    const int hseg = t & 3;
    const int c0   = hseg << 3;               // local col in half: 0,8,16,24
    const unsigned rowBase = base + ((unsigned)hr << 9);
    // Vertical mapping: thread -> (col vcol 0..31, 8-row stripe)
    const int vcol = t & 31;
    const int vr0  = (t >> 5) << 3;           // padded window start row

    float accS = 0.f;

    for (int h = 0; h < 2; ++h) {
        const int g0 = (h << 5) + c0;         // global col of first output
        // ---------------- Horizontal pass (one half) -----------------------
        // Window taps for global cols g0-5 .. g0+12 (18 floats); aligned
        // float4 loads cover g0-8 .. g0+15, extras discarded at compile time.
        // s=x+y, d=x-y built at extraction; x,y never live as arrays.
        float s[18], d[18];
        #pragma unroll
        for (int m = 0; m < 6; ++m) {
            const int cb = g0 - 8 + 4 * m;    // global col of this float4
            float4 xv = make_float4(0.f, 0.f, 0.f, 0.f);
            float4 yv = make_float4(0.f, 0.f, 0.f, 0.f);
            if (cb >= 0 && cb < 64) {         // zero pad outside patch
                xv = *(const float4*)(Nimg + rowBase + cb);
                yv = *(const float4*)(GT   + rowBase + cb);
            }
            #pragma unroll
            for (int u = 0; u < 4; ++u) {
                const int j = 4 * m + u - 3;  // window index (col g0-5+j)
                if (j >= 0 && j < 18) {
                    s[j] = (&xv.x)[u] + (&yv.x)[u];
                    d[j] = (&xv.x)[u] - (&yv.x)[u];
                }
            }
        }

        // conv(s) -> S2, then square s IN PLACE, conv(s^2) -> S0;
        // conv(d) -> S3, square d in place, conv(d^2) -> S1.
        #pragma unroll
        for (int mm = 0; mm < 2; ++mm) {
            float4 o;
            #pragma unroll
            for (int u = 0; u < 4; ++u) (&o.x)[u] = conv11(&s[4*mm + u]);
            *(float4*)&S2[5 + hr][c0 + 4*mm] = o;
        }
        #pragma unroll
        for (int i = 0; i < 18; ++i) s[i] = s[i] * s[i];
        #pragma unroll
        for (int mm = 0; mm < 2; ++mm) {
            float4 o;
            #pragma unroll
            for (int u = 0; u < 4; ++u) (&o.x)[u] = conv11(&s[4*mm + u]);
            *(float4*)&S0[5 + hr][c0 + 4*mm] = o;
        }
        #pragma unroll
        for (int mm = 0; mm < 2; ++mm) {
            float4 o;
            #pragma unroll
            for (int u = 0; u < 4; ++u) (&o.x)[u] = conv11(&d[4*mm + u]);
            *(float4*)&S3[5 + hr][c0 + 4*mm] = o;
        }
        #pragma unroll
        for (int i = 0; i < 18; ++i) d[i] = d[i] * d[i];
        #pragma unroll
        for (int mm = 0; mm < 2; ++mm) {
            float4 o;
            #pragma unroll
            for (int u = 0; u < 4; ++u) (&o.x)[u] = conv11(&d[4*mm + u]);
            *(float4*)&S1[5 + hr][c0 + 4*mm] = o;
        }
        __syncthreads();

        // ---------------- Vertical pass: 4 convs + SSIM --------------------
        {
            float t2[8], ss[8], uv[8];       // 2*mu1mu2, mu1^2+mu2^2, conv(s^2)
            float w[18];
            #pragma unroll
            for (int dd = 0; dd < 18; ++dd) w[dd] = S2[vr0 + dd][vcol];
            #pragma unroll
            for (int o = 0; o < 8; ++o) t2[o] = conv11(&w[o]);   // a, temp
            #pragma unroll
            for (int dd = 0; dd < 18; ++dd) w[dd] = S3[vr0 + dd][vcol];
            #pragma unroll
            for (int o = 0; o < 8; ++o) {
                const float bb = conv11(&w[o]);                  // b
                const float A2 = t2[o] * t2[o];
                const float B2 = bb * bb;
                t2[o] = 0.5f * (A2 - B2);                        // 2*mu1*mu2
                ss[o] = 0.5f * (A2 + B2);                        // mu1^2+mu2^2
            }
            #pragma unroll
            for (int dd = 0; dd < 18; ++dd) w[dd] = S0[vr0 + dd][vcol];
            #pragma unroll
            for (int o = 0; o < 8; ++o) uv[o] = conv11(&w[o]);   // u
            #pragma unroll
            for (int dd = 0; dd < 18; ++dd) w[dd] = S1[vr0 + dd][vcol];
            #pragma unroll
            for (int o = 0; o < 8; ++o) {
                const float vvv  = conv11(&w[o]);                // v
                const float numL = t2[o] + C1C;
                const float denL = ss[o] + C1C;
                const float numR = fmaf(0.5f, uv[o] - vvv, C2C - t2[o]);
                const float denR = fmaf(0.5f, uv[o] + vvv, C2C - ss[o]);
                // rcp: rel err ~1e-6, final scalar well within tolerance
                accS += (numL * numR) * __builtin_amdgcn_rcpf(denL * denR);
            }
        }
        __syncthreads();      // buffers free for next half (or reduction)
    }

    // ---------------- Fused MSE partials over this plane -------------------
    float sa = 0.f, sbg = 0.f;
    #pragma unroll
    for (int it = 0; it < 4; ++it) {
        const int idx  = t + 256 * it;        // 0..1023 float4 slots
        const int row  = idx >> 4;
        const int col4 = (idx & 15) << 2;
        const unsigned off = base + ((unsigned)row << 9) + col4;
        const float4 av  = *(const float4*)(A  + off);
        const float4 gv  = *(const float4*)(G  + off);
        const float4 bgv = *(const float4*)(BG + off);
        float d0 = bgv.x - gv.x, d1 = bgv.y - gv.y, d2 = bgv.z - gv.z, d3 = bgv.w - gv.w;
        sbg += d0*d0 + d1*d1 + d2*d2 + d3*d3;
        float e0 = av.x - gv.x, e1 = av.y - gv.y, e2 = av.z - gv.z, e3 = av.w - gv.w;
        sa  += e0*e0 + e1*e1 + e2*e2 + e3*e3;
    }

    // ---------------- Block reduction of (accS, sa, sbg) -------------------
    #pragma unroll
    for (int off = 32; off; off >>= 1) {
        accS += __shfl_down(accS, off, 64);
        sa   += __shfl_down(sa,   off, 64);
        sbg  += __shfl_down(sbg,  off, 64);
    }
    const int wv = t >> 6;
    if ((t & 63) == 0) {
        S0[0][wv] = accS; S0[1][wv] = sa; S0[2][wv] = sbg;
    }
    __syncthreads();
    if (t == 0) {
        const int plane = q * 3 + c;
        ssim_sum[plane] = S0[0][0] + S0[0][1] + S0[0][2] + S0[0][3];
        sa_sum[plane]   = S0[1][0] + S0[1][1] + S0[1][2] + S0[1][3];
        sbg_sum[plane]  = S0[2][0] + S0[2][1] + S0[2][2] + S0[2][3];
    }
}

// ---------------------------------------------------------------------------
// Final combine: 1 block, 256 threads, no atomics, deterministic.
// ---------------------------------------------------------------------------
__global__ __launch_bounds__(256) void combine_kernel(
    const float* __restrict__ ssim_sum, const float* __restrict__ sa_sum,
    const float* __restrict__ sbg_sum, float* __restrict__ out)
{
    __shared__ float red[4];
    const int t = threadIdx.x;
    const float invN = 1.f / 12288.f;     // 3*64*64
    float acc = 0.f;
    #pragma unroll
    for (int r = 0; r < 8; ++r) {
        const int qq = t + 256 * r;       // patch 0..2047
        const float ss = ssim_sum[3*qq] + ssim_sum[3*qq+1] + ssim_sum[3*qq+2];
        const float sa = sa_sum[3*qq]   + sa_sum[3*qq+1]   + sa_sum[3*qq+2];
        const float sb = sbg_sum[3*qq]  + sbg_sum[3*qq+1]  + sbg_sum[3*qq+2];
        const float ssim = ss * invN;
        const float diff = fminf(1.f - ssim, 1.f);     // LD = 1.0
        acc += diff * (sb * invN) + (1.f - diff) * (sa * invN);
    }
    #pragma unroll
    for (int off = 32; off; off >>= 1) acc += __shfl_down(acc, off, 64);
    if ((t & 63) == 0) red[t >> 6] = acc;
    __syncthreads();
    if (t == 0) out[0] = red[0] + red[1] + red[2] + red[3];
}

extern "C" void kernel_launch(void* const* d_in, const int* in_sizes, int n_in,
                              void* d_out, int out_size, void* d_ws, size_t ws_size,
                              hipStream_t stream) {
    const float* A  = (const float*)d_in[0];
    const float* Nn = (const float*)d_in[1];
    const float* GT = (const float*)d_in[2];
    const float* G  = (const float*)d_in[3];
    const float* BG = (const float*)d_in[4];
    float* out      = (float*)d_out;

    float* ssim_sum = (float*)d_ws;            // 6144 floats
    float* sa_sum   = ssim_sum + 6144;         // 6144 floats
    float* sbg_sum  = ssim_sum + 12288;        // 6144 floats

    ssim_fused_kernel<<<dim3(2048, 3), 256, 0, stream>>>(
        A, Nn, GT, G, BG, ssim_sum, sa_sum, sbg_sum);
    combine_kernel<<<1, 256, 0, stream>>>(ssim_sum, sa_sum, sbg_sum, out);
}